// Round 12
// baseline (110.895 us; speedup 1.0000x reference)
//
#include <hip/hip_runtime.h>

// Bicubic (Catmull-Rom) warped interpolation, LDS-tiled (R11 layout).
// img/delta_x/delta_y: [B,C,H,W] fp32; out: fp32 clipped to [0,1]. H=W=1024.
// 64x64 output tile per 512-THREAD block (8 waves): same 80x80 fp32 patch,
// stride 96 (mod 32 == 0 -> bank = lane + x-jitter only; R11 win), but 2x
// waves per block -> 4 blocks x 512 = 2048 threads/CU = 100% occupancy
// potential (vs 52%): more resident waves interleave the LDS-issue pipe and
// the VALU pipe, which round-11 analysis showed are two ~60us serial-ish
// streams at 52% occupancy. Lane = column; per-wave rows 0..7, 8 iters
// stride 8. Delta loads hoisted (R6 win). Rare fp32 global fallback.

#define HD 1024
#define WD 1024
#define TILE 64
#define HALO 8
#define SROWS 80   // staged rows & cols of valid data
#define SSTR 96    // LDS row stride in floats; 96 % 32 == 0 -> bank = lx % 32

__device__ __forceinline__ float cubic_gather_global(
    const float* __restrict__ p, int x0, int y0,
    float wxm1, float wx0, float wx1, float wx2,
    float wym1, float wy0, float wy1, float wy2)
{
    int cx0 = min(max(x0 - 1, 0), WD - 1);
    int cx1 = min(max(x0,     0), WD - 1);
    int cx2 = min(max(x0 + 1, 0), WD - 1);
    int cx3 = min(max(x0 + 2, 0), WD - 1);
    int cy0 = min(max(y0 - 1, 0), HD - 1);
    int cy1 = min(max(y0,     0), HD - 1);
    int cy2 = min(max(y0 + 1, 0), HD - 1);
    int cy3 = min(max(y0 + 2, 0), HD - 1);
    const float* r0 = p + (size_t)cy0 * WD;
    const float* r1 = p + (size_t)cy1 * WD;
    const float* r2 = p + (size_t)cy2 * WD;
    const float* r3 = p + (size_t)cy3 * WD;
    float s0 = wxm1 * r0[cx0] + wx0 * r0[cx1] + wx1 * r0[cx2] + wx2 * r0[cx3];
    float s1 = wxm1 * r1[cx0] + wx0 * r1[cx1] + wx1 * r1[cx2] + wx2 * r1[cx3];
    float s2 = wxm1 * r2[cx0] + wx0 * r2[cx1] + wx1 * r2[cx2] + wx2 * r2[cx3];
    float s3 = wxm1 * r3[cx0] + wx0 * r3[cx1] + wx1 * r3[cx2] + wx2 * r3[cx3];
    return wym1 * s0 + wy0 * s1 + wy1 * s2 + wy2 * s3;
}

__global__ __launch_bounds__(512) void bicubic_tile_kernel(
    const float* __restrict__ img,
    const float* __restrict__ dxp,
    const float* __restrict__ dyp,
    float* __restrict__ out)
{
    __shared__ float sm[SROWS * SSTR];   // 30.7 KB -> 4 blocks/CU (thread-cap)

    const int bx = blockIdx.x * TILE;
    const int by = blockIdx.y * TILE;
    const int plane = blockIdx.z;
    const float* __restrict__ p = img + (size_t)plane * (size_t)(HD * WD);

    const int gx0 = bx - HALO;
    const int gy0 = by - HALO;
    const int tid = threadIdx.x;

    // ---- stage 80x80 patch at (gy0, gx0) into LDS (edge-clamped) ----
    if (gx0 >= 0 && gx0 + SROWS <= WD) {
        for (int s = tid; s < SROWS * (SROWS / 4); s += 512) {
            int r = s / (SROWS / 4);
            int q = s - r * (SROWS / 4);
            int gy = min(max(gy0 + r, 0), HD - 1);
            float4 v = *reinterpret_cast<const float4*>(p + (size_t)gy * WD + gx0 + 4 * q);
            int b = r * SSTR + 4 * q;
            sm[b + 0] = v.x; sm[b + 1] = v.y; sm[b + 2] = v.z; sm[b + 3] = v.w;
        }
    } else {
        for (int s = tid; s < SROWS * SROWS; s += 512) {
            int r = s / SROWS;
            int c = s - r * SROWS;
            int gy = min(max(gy0 + r, 0), HD - 1);
            int gx = min(max(gx0 + c, 0), WD - 1);
            sm[r * SSTR + c] = p[(size_t)gy * WD + gx];
        }
    }
    __syncthreads();

    // ---- compute: lane = column; wave w owns rows w, w+8, ..., w+56
    const int col = bx + (tid & 63);
    const int rbase = by + (tid >> 6);         // wave id 0..7
    const int didx0 = (plane << 20) | (rbase << 10) | col;

    // hoisted delta loads (R6 win: HBM latency hides under compute)
    float vdx[8], vdy[8];
    #pragma unroll
    for (int it = 0; it < 8; ++it) {
        vdx[it] = dxp[didx0 + it * 8192];
        vdy[it] = dyp[didx0 + it * 8192];
    }

    // x_map = ((x + dx - 512)/511 + 1)*511.5 == (x-512)*sc + 511.5 + dx*sc
    const float sc = 511.5f / 511.0f;
    const float colA = ((float)col - 512.0f) * sc + 511.5f;
    const float yA0 = ((float)rbase - 512.0f) * sc + 511.5f;
    const float yStep = 8.0f * sc;

    #pragma unroll
    for (int it = 0; it < 8; ++it) {
        const int didx = didx0 + it * 8192;
        const float ddx = vdx[it];
        const float ddy = vdy[it];

        float x_map = fmaf(ddx, sc, colA);
        float y_map = fmaf(ddy, sc, yA0 + (float)it * yStep);

        float x0f = floorf(x_map);
        float y0f = floorf(y_map);
        float tx = x_map - x0f;
        float ty = y_map - y0f;
        int x0 = (int)x0f;
        int y0 = (int)y0f;

        float tx2 = tx * tx, tx3 = tx2 * tx;
        float wxm1 = (-tx3 + 2.0f * tx2 - tx) * 0.5f;
        float wx0  = (3.0f * tx3 - 5.0f * tx2 + 2.0f) * 0.5f;
        float wx1  = (-3.0f * tx3 + 4.0f * tx2 + tx) * 0.5f;
        float wx2  = 1.0f - (wxm1 + wx0 + wx1);

        float ty2 = ty * ty, ty3 = ty2 * ty;
        float wym1 = (-ty3 + 2.0f * ty2 - ty) * 0.5f;
        float wy0  = (3.0f * ty3 - 5.0f * ty2 + 2.0f) * 0.5f;
        float wy1  = (-3.0f * ty3 + 4.0f * ty2 + ty) * 0.5f;
        float wy2  = 1.0f - (wym1 + wy0 + wy1);

        // raw tap window (LDS holds edge-clamped values; no per-tap clamps)
        const int lx = x0 - 1 - gx0;
        const int ly = y0 - 1 - gy0;
        const bool inb = (lx >= 0) & (lx <= SROWS - 4) & (ly >= 0) & (ly <= SROWS - 4);

        float acc;
        if (inb) {
            const float* b = &sm[ly * SSTR + lx];
            float s0 = wxm1 * b[0 * SSTR + 0] + wx0 * b[0 * SSTR + 1] + wx1 * b[0 * SSTR + 2] + wx2 * b[0 * SSTR + 3];
            float s1 = wxm1 * b[1 * SSTR + 0] + wx0 * b[1 * SSTR + 1] + wx1 * b[1 * SSTR + 2] + wx2 * b[1 * SSTR + 3];
            float s2 = wxm1 * b[2 * SSTR + 0] + wx0 * b[2 * SSTR + 1] + wx1 * b[2 * SSTR + 2] + wx2 * b[2 * SSTR + 3];
            float s3 = wxm1 * b[3 * SSTR + 0] + wx0 * b[3 * SSTR + 1] + wx1 * b[3 * SSTR + 2] + wx2 * b[3 * SSTR + 3];
            acc = wym1 * s0 + wy0 * s1 + wy1 * s2 + wy2 * s3;
        } else {
            acc = cubic_gather_global(p, x0, y0, wxm1, wx0, wx1, wx2,
                                      wym1, wy0, wy1, wy2);
        }
        out[didx] = fminf(fmaxf(acc, 0.0f), 1.0f);
    }
}

extern "C" void kernel_launch(void* const* d_in, const int* in_sizes, int n_in,
                              void* d_out, int out_size, void* d_ws, size_t ws_size,
                              hipStream_t stream) {
    const float* img = (const float*)d_in[0];
    const float* dxp = (const float*)d_in[1];
    const float* dyp = (const float*)d_in[2];
    float* out = (float*)d_out;

    const int planes = in_sizes[0] / (HD * WD);  // B*C = 24
    dim3 grid(WD / TILE, HD / TILE, planes);
    bicubic_tile_kernel<<<grid, 512, 0, stream>>>(img, dxp, dyp, out);
}

// Round 13
// 89.440 us; speedup vs baseline: 1.2399x; 1.2399x over previous
//
#include <hip/hip_runtime.h>

// Bicubic (Catmull-Rom) warped interpolation, LDS-tiled (R11 layout) +
// packed-fp32 math (v_pk_fma_f32) + paired LDS reads (ds_read2_b32).
// img/delta_x/delta_y: [B,C,H,W] fp32; out: fp32 clipped to [0,1]. H=W=1024.
// 64x64 tile / 256 threads; 80x80 fp32 patch, stride 96 (bank = lane+x-jitter
// only; R11 win). Weight polynomials computed for (tx,ty) TOGETHER as float2
// ext-vectors -> VOP3P packed f32 (12 packed ops vs ~26 scalar). Tap rows
// paired (k,k+1) at same x via sm[a]/sm[a+96] -> one ds_read2_b32 into a
// VGPR pair, consumed directly by packed FMA (8 LDS instr + 8 pk_fma vs
// 16 + 16). Round-11 analysis: LDS pipe and VALU pipe serialize (sum of
// their times == profiled dur), so cutting both cuts wall time ~linearly.
// Delta loads hoisted (R6 win). Rare fp32 global fallback for |delta| > ~6.

#define HD 1024
#define WD 1024
#define TILE 64
#define HALO 8
#define SROWS 80   // staged rows & cols of valid data
#define SSTR 96    // LDS row stride in floats; 96 % 32 == 0 -> bank = lx % 32

typedef __attribute__((ext_vector_type(2))) float f32x2;

__device__ __forceinline__ float cubic_gather_global(
    const float* __restrict__ p, int x0, int y0,
    float wxm1, float wx0, float wx1, float wx2,
    float wym1, float wy0, float wy1, float wy2)
{
    int cx0 = min(max(x0 - 1, 0), WD - 1);
    int cx1 = min(max(x0,     0), WD - 1);
    int cx2 = min(max(x0 + 1, 0), WD - 1);
    int cx3 = min(max(x0 + 2, 0), WD - 1);
    int cy0 = min(max(y0 - 1, 0), HD - 1);
    int cy1 = min(max(y0,     0), HD - 1);
    int cy2 = min(max(y0 + 1, 0), HD - 1);
    int cy3 = min(max(y0 + 2, 0), HD - 1);
    const float* r0 = p + (size_t)cy0 * WD;
    const float* r1 = p + (size_t)cy1 * WD;
    const float* r2 = p + (size_t)cy2 * WD;
    const float* r3 = p + (size_t)cy3 * WD;
    float s0 = wxm1 * r0[cx0] + wx0 * r0[cx1] + wx1 * r0[cx2] + wx2 * r0[cx3];
    float s1 = wxm1 * r1[cx0] + wx0 * r1[cx1] + wx1 * r1[cx2] + wx2 * r1[cx3];
    float s2 = wxm1 * r2[cx0] + wx0 * r2[cx1] + wx1 * r2[cx2] + wx2 * r2[cx3];
    float s3 = wxm1 * r3[cx0] + wx0 * r3[cx1] + wx1 * r3[cx2] + wx2 * r3[cx3];
    return wym1 * s0 + wy0 * s1 + wy1 * s2 + wy2 * s3;
}

__global__ __launch_bounds__(256) void bicubic_tile_kernel(
    const float* __restrict__ img,
    const float* __restrict__ dxp,
    const float* __restrict__ dyp,
    float* __restrict__ out)
{
    __shared__ float sm[SROWS * SSTR];   // 30.7 KB

    const int bx = blockIdx.x * TILE;
    const int by = blockIdx.y * TILE;
    const int plane = blockIdx.z;
    const float* __restrict__ p = img + (size_t)plane * (size_t)(HD * WD);

    const int gx0 = bx - HALO;
    const int gy0 = by - HALO;
    const int tid = threadIdx.x;

    // ---- stage 80x80 patch at (gy0, gx0) into LDS (edge-clamped) ----
    if (gx0 >= 0 && gx0 + SROWS <= WD) {
        for (int s = tid; s < SROWS * (SROWS / 4); s += 256) {
            int r = s / (SROWS / 4);
            int q = s - r * (SROWS / 4);
            int gy = min(max(gy0 + r, 0), HD - 1);
            float4 v = *reinterpret_cast<const float4*>(p + (size_t)gy * WD + gx0 + 4 * q);
            int b = r * SSTR + 4 * q;
            sm[b + 0] = v.x; sm[b + 1] = v.y; sm[b + 2] = v.z; sm[b + 3] = v.w;
        }
    } else {
        for (int s = tid; s < SROWS * SROWS; s += 256) {
            int r = s / SROWS;
            int c = s - r * SROWS;
            int gy = min(max(gy0 + r, 0), HD - 1);
            int gx = min(max(gx0 + c, 0), WD - 1);
            sm[r * SSTR + c] = p[(size_t)gy * WD + gx];
        }
    }
    __syncthreads();

    // ---- compute: lane = column (64 consecutive cols/wave), 16 rows/thread
    const int col = bx + (tid & 63);
    const int rbase = by + (tid >> 6);
    const int didx0 = (plane << 20) | (rbase << 10) | col;

    // hoisted delta loads (R6 win: HBM latency hides under compute)
    float vdx[16], vdy[16];
    #pragma unroll
    for (int it = 0; it < 16; ++it) {
        vdx[it] = dxp[didx0 + it * 4096];
        vdy[it] = dyp[didx0 + it * 4096];
    }

    // x_map = ((x + dx - 512)/511 + 1)*511.5 == (x-512)*sc + 511.5 + dx*sc
    const float sc = 511.5f / 511.0f;
    const float colA = ((float)col - 512.0f) * sc + 511.5f;
    const float yA0 = ((float)rbase - 512.0f) * sc + 511.5f;
    const float yStep = 4.0f * sc;

    // packed polynomial constants
    const f32x2 cN05 = {-0.5f, -0.5f};
    const f32x2 cP05 = { 0.5f,  0.5f};
    const f32x2 cP1  = { 1.0f,  1.0f};
    const f32x2 cN1  = {-1.0f, -1.0f};
    const f32x2 cP2  = { 2.0f,  2.0f};
    const f32x2 cN25 = {-2.5f, -2.5f};
    const f32x2 cP15 = { 1.5f,  1.5f};
    const f32x2 cN15 = {-1.5f, -1.5f};

    #pragma unroll
    for (int it = 0; it < 16; ++it) {
        const int didx = didx0 + it * 4096;
        const float ddx = vdx[it];
        const float ddy = vdy[it];

        float x_map = fmaf(ddx, sc, colA);
        float y_map = fmaf(ddy, sc, yA0 + (float)it * yStep);

        float x0f = floorf(x_map);
        float y0f = floorf(y_map);
        int x0 = (int)x0f;
        int y0 = (int)y0f;

        // packed weights: lane .x = x-direction, lane .y = y-direction
        f32x2 t;
        t.x = x_map - x0f;
        t.y = y_map - y0f;
        f32x2 t2v = t * t;
        f32x2 t3v = t2v * t;
        // wm1 = -0.5 t3 + t2 - 0.5 t
        f32x2 wm1 = __builtin_elementwise_fma(t3v, cN05,
                        __builtin_elementwise_fma(t, cN05, t2v));
        // w0 = 1.5 t3 - 2.5 t2 + 1
        f32x2 w0v = __builtin_elementwise_fma(t3v, cP15,
                        __builtin_elementwise_fma(t2v, cN25, cP1));
        // w1 = -1.5 t3 + 2 t2 + 0.5 t
        f32x2 w1v = __builtin_elementwise_fma(t3v, cN15,
                        __builtin_elementwise_fma(t2v, cP2, t * cP05));
        // w2 = 1 - (wm1 + w0 + w1)
        f32x2 w2v = __builtin_elementwise_fma(wm1 + w0v + w1v, cN1, cP1);

        const int lx = x0 - 1 - gx0;
        const int ly = y0 - 1 - gy0;
        const bool inb = (lx >= 0) & (lx <= SROWS - 4) & (ly >= 0) & (ly <= SROWS - 4);

        float acc;
        if (inb) {
            const float* b  = &sm[ly * SSTR + lx];
            const float* b2 = b + 2 * SSTR;
            // row-pairs at same x -> ds_read2_b32 (offset0:j offset1:96+j)
            f32x2 q0, q1, q2, q3, r0, r1, r2, r3;
            q0.x = b[0];  q0.y = b[SSTR + 0];
            q1.x = b[1];  q1.y = b[SSTR + 1];
            q2.x = b[2];  q2.y = b[SSTR + 2];
            q3.x = b[3];  q3.y = b[SSTR + 3];
            r0.x = b2[0]; r0.y = b2[SSTR + 0];
            r1.x = b2[1]; r1.y = b2[SSTR + 1];
            r2.x = b2[2]; r2.y = b2[SSTR + 2];
            r3.x = b2[3]; r3.y = b2[SSTR + 3];
            // packed horizontal combine: s01 = (s_row0, s_row1), s23 = (s_row2, s_row3)
            f32x2 s01 = __builtin_elementwise_fma(w2v.xx, q3,
                            __builtin_elementwise_fma(w1v.xx, q2,
                                __builtin_elementwise_fma(w0v.xx, q1, wm1.xx * q0)));
            f32x2 s23 = __builtin_elementwise_fma(w2v.xx, r3,
                            __builtin_elementwise_fma(w1v.xx, r2,
                                __builtin_elementwise_fma(w0v.xx, r1, wm1.xx * r0)));
            // vertical combine (scalar, 4 ops)
            acc = wm1.y * s01.x + w0v.y * s01.y + w1v.y * s23.x + w2v.y * s23.y;
        } else {
            acc = cubic_gather_global(p, x0, y0, wm1.x, w0v.x, w1v.x, w2v.x,
                                      wm1.y, w0v.y, w1v.y, w2v.y);
        }
        out[didx] = fminf(fmaxf(acc, 0.0f), 1.0f);
    }
}

extern "C" void kernel_launch(void* const* d_in, const int* in_sizes, int n_in,
                              void* d_out, int out_size, void* d_ws, size_t ws_size,
                              hipStream_t stream) {
    const float* img = (const float*)d_in[0];
    const float* dxp = (const float*)d_in[1];
    const float* dyp = (const float*)d_in[2];
    float* out = (float*)d_out;

    const int planes = in_sizes[0] / (HD * WD);  // B*C = 24
    dim3 grid(WD / TILE, HD / TILE, planes);
    bicubic_tile_kernel<<<grid, 256, 0, stream>>>(img, dxp, dyp, out);
}